// Round 1
// baseline (276.060 us; speedup 1.0000x reference)
//
#include <hip/hip_runtime.h>

// Problem constants
#define N_ROWS 16384   // B*T
#define C_DIM  1024
#define GV     640     // G*V
#define V_DIM  320
#define G_DIM  2
#define D_DIM  256
#define MROWS  64      // rows per fused block (was 32)
#define FBLKS  (N_ROWS / MROWS)  // 256 = exactly 1 block/CU
#define NBUCKET 64

typedef __attribute__((ext_vector_type(8))) _Float16 half8;
typedef __attribute__((ext_vector_type(4))) _Float16 half4v;
typedef __attribute__((ext_vector_type(4))) float float4v;

#define LDS_AS(p) ((__attribute__((address_space(3))) unsigned int*)(p))
#define GLB_AS(p) ((const __attribute__((address_space(1))) unsigned int*)(p))

// ---------------- W -> fp16 hi, pre-swizzled into 16B-chunk-transposed layout ----
// whT[((kb*4 + c)*640 + n)*8 + h] = (half)W[n][kb*32 + c*8 + h]
// (unchanged from previous version; fused kernel stages this linearly per K-iter)
__global__ __launch_bounds__(256) void wsplit_kernel(const float* __restrict__ src,
                                                     _Float16* __restrict__ dst) {
  const int t = blockIdx.x * 256 + threadIdx.x;  // 0..81919
  const int n = t % GV;
  const int cc = t / GV;       // 0..127 ; k = cc*8
  const int k = cc * 8;
  const float4 v0 = *(const float4*)(src + (size_t)n * C_DIM + k);
  const float4 v1 = *(const float4*)(src + (size_t)n * C_DIM + k + 4);
  half8 h;
  h[0] = (_Float16)v0.x; h[1] = (_Float16)v0.y; h[2] = (_Float16)v0.z; h[3] = (_Float16)v0.w;
  h[4] = (_Float16)v1.x; h[5] = (_Float16)v1.y; h[6] = (_Float16)v1.z; h[7] = (_Float16)v1.w;
  *(half8*)(dst + (size_t)t * 8) = h;
}

// ---------------- Fused: GEMM (M=64 x N=640 per block) + row ops ----------------
// Double-buffered LDS staging, ONE barrier per K-iter: next-iter loads are issued
// before this iter's MFMA phase, so the vmcnt(0) drain at __syncthreads finds
// them already complete (minimum 2-phase pipeline).
__global__ __launch_bounds__(512, 2) void fused_kernel(
    const float* __restrict__ x,       // [N_ROWS, C_DIM] fp32
    const _Float16* __restrict__ whT,  // swizzled fp16 hi of W
    const float* __restrict__ bias,    // [GV]
    const float* __restrict__ gn,      // [2*N_ROWS, V_DIM]
    const float* __restrict__ cb,      // [GV, D_DIM]
    float* __restrict__ q,             // [N_ROWS, 512]
    float* __restrict__ mf,            // [NBUCKET, GV] atomic softmax partials (pre-zeroed)
    int* __restrict__ mi) {            // [NBUCKET, GV] atomic argmax counts (pre-zeroed)
  // LDS map (bytes):
  //  [0      , 81920): B hi, 2 buffers x 40960  ([c][n] 16B chunks)
  //  [81920  , 90112): A hi, 2 buffers x 4096   ([c][row] 8B half-chunks)
  //  [90112  , 98304): A lo, 2 buffers x 4096
  //  epilogue: Ldump = 64 x 321 fp32 (82176 B) reuses [0, 82176)
  __shared__ __align__(16) char smemU[98304];
  _Float16* BhL = (_Float16*)smemU;
  _Float16* AhL = (_Float16*)(smemU + 81920);
  _Float16* AlL = (_Float16*)(smemU + 90112);
  float* Ldump  = (float*)smemU;
  __shared__ float accL[GV];
  __shared__ int   cntL[GV];

  const int tid = threadIdx.x;
  const int lane = tid & 63;
  const int w = tid >> 6;          // wave 0..7
  const int m0 = blockIdx.x * MROWS;
  const int frow = lane & 15;
  const int quad = lane >> 4;

  for (int e = tid; e < GV; e += 512) { accL[e] = 0.0f; cntL[e] = 0; }

  // A staging map: thread -> (row ar, 4-float k-chunk ak) of 64x32 fp32 tile
  const int ar = tid >> 3;           // 0..63
  const int ak = (tid & 7) * 4;      // 0,4,...,28
  const int ac = ak >> 3;            // chunk 0..3
  const int ah_off = ak & 7;         // 0 or 4 within 8-half chunk
  const float* xp = x + (size_t)(m0 + ar) * C_DIM + ak;

  float4v acc[4][5];
#pragma unroll
  for (int i = 0; i < 4; ++i)
#pragma unroll
    for (int j = 0; j < 5; ++j) acc[i][j] = (float4v)0.0f;

  // ---- staging helpers ----
  auto stageB = [&](int kb, _Float16* Bh) {
    const _Float16* bsrc = whT + (size_t)kb * 2560 * 8;
#pragma unroll
    for (int s = 0; s < 5; ++s) {
      const int c = s * 512 + tid;   // 2560 16B chunks, lane-linear both sides
      __builtin_amdgcn_global_load_lds(GLB_AS(bsrc + (size_t)c * 8),
                                       LDS_AS(Bh + c * 8), 16, 0, 0);
    }
  };
  auto splitA = [&](const float4& a4, _Float16* Ah, _Float16* Al) {
    const _Float16 h0 = (_Float16)a4.x, h1 = (_Float16)a4.y;
    const _Float16 h2 = (_Float16)a4.z, h3 = (_Float16)a4.w;
    half4v hv, lv;
    hv[0] = h0; hv[1] = h1; hv[2] = h2; hv[3] = h3;
    lv[0] = (_Float16)(a4.x - (float)h0);
    lv[1] = (_Float16)(a4.y - (float)h1);
    lv[2] = (_Float16)(a4.z - (float)h2);
    lv[3] = (_Float16)(a4.w - (float)h3);
    *(half4v*)&Ah[(ac * 64 + ar) * 8 + ah_off] = hv;
    *(half4v*)&Al[(ac * 64 + ar) * 8 + ah_off] = lv;
  };

  // ---- prologue: fill buffer 0, prefetch A regs for kb=1 ----
  float4 a4 = *(const float4*)xp;
  stageB(0, BhL);
  splitA(a4, AhL, AlL);
  a4 = *(const float4*)(xp + 32);
  __syncthreads();

  // ---- main loop: 32 K-iters, single barrier each ----
  for (int kb = 0; kb < 32; ++kb) {
    const int cur = kb & 1;
    _Float16* BhC = BhL + cur * 20480;
    _Float16* AhC = AhL + cur * 2048;
    _Float16* AlC = AlL + cur * 2048;

    // issue next-iter staging into the other buffer BEFORE compute
    if (kb < 31) {
      const int nxt = cur ^ 1;
      stageB(kb + 1, BhL + nxt * 20480);
      splitA(a4, AhL + nxt * 2048, AlL + nxt * 2048);
      if (kb < 30) a4 = *(const float4*)(xp + (kb + 2) * 32);
    }

    half8 ah[4], al[4];
#pragma unroll
    for (int i = 0; i < 4; ++i) {
      ah[i] = *(const half8*)&AhC[(quad * 64 + 16 * i + frow) * 8];
      al[i] = *(const half8*)&AlC[(quad * 64 + 16 * i + frow) * 8];
    }
#pragma unroll
    for (int j = 0; j < 5; ++j) {
      const half8 bh = *(const half8*)&BhC[(quad * 640 + 80 * w + 16 * j + frow) * 8];
#pragma unroll
      for (int i = 0; i < 4; ++i) {
        acc[i][j] = __builtin_amdgcn_mfma_f32_16x16x32_f16(ah[i], bh, acc[i][j], 0, 0, 0);
        acc[i][j] = __builtin_amdgcn_mfma_f32_16x16x32_f16(al[i], bh, acc[i][j], 0, 0, 0);
      }
    }
    __syncthreads();  // drains the early-issued loads (cheap) + protects buffer swap
  }

  // bias for this wave's cols
  float bw[5];
#pragma unroll
  for (int j = 0; j < 5; ++j) bw[j] = bias[80 * w + 16 * j + frow];

  // -------- epilogue: two group phases --------
#pragma unroll
  for (int g = 0; g < G_DIM; ++g) {
    __syncthreads();  // staging/prev-phase LDS dead
    if ((w >> 2) == g) {
      const int cg0 = 80 * (w & 3) + frow;
#pragma unroll
      for (int i = 0; i < 4; ++i)
#pragma unroll
        for (int j = 0; j < 5; ++j)
#pragma unroll
          for (int r = 0; r < 4; ++r)
            Ldump[(16 * i + 4 * quad + r) * 321 + cg0 + 16 * j] = acc[i][j][r] + bw[j];
    }
    __syncthreads();

    float pacc5[5] = {0.0f, 0.0f, 0.0f, 0.0f, 0.0f};
#pragma unroll
    for (int rr = 0; rr < 8; ++rr) {
      const int row = w * 8 + rr;
      const int n = m0 + row;
      const float* gp = gn + (size_t)(2 * n + g) * V_DIM;

      float l[5], t[5];
#pragma unroll
      for (int j = 0; j < 5; ++j) {
        l[j] = Ldump[row * 321 + lane + 64 * j];
        t[j] = (l[j] + gp[lane + 64 * j]) * 0.5f;
      }

      // argmax of l (first index on ties)
      float m = l[0]; int mi_ = lane;
#pragma unroll
      for (int j = 1; j < 5; ++j) {
        const int v = lane + 64 * j;
        if (l[j] > m) { m = l[j]; mi_ = v; }
      }
#pragma unroll
      for (int off = 32; off > 0; off >>= 1) {
        const float om = __shfl_xor(m, off, 64);
        const int omi = __shfl_xor(mi_, off, 64);
        if (om > m || (om == m && omi < mi_)) { m = om; mi_ = omi; }
      }
      if (lane == 0) atomicAdd(&cntL[g * V_DIM + mi_], 1);

      // softmax of l
      float e[5], s = 0.0f;
#pragma unroll
      for (int j = 0; j < 5; ++j) { e[j] = expf(l[j] - m); s += e[j]; }
#pragma unroll
      for (int off = 32; off > 0; off >>= 1) s += __shfl_xor(s, off, 64);
      const float inv = 1.0f / s;
#pragma unroll
      for (int j = 0; j < 5; ++j) pacc5[j] += e[j] * inv;

      // gumbel path
      float tm = t[0]; int ti = lane;
#pragma unroll
      for (int j = 1; j < 5; ++j) {
        const int v = lane + 64 * j;
        if (t[j] > tm) { tm = t[j]; ti = v; }
      }
#pragma unroll
      for (int off = 32; off > 0; off >>= 1) {
        const float om = __shfl_xor(tm, off, 64);
        const int omi = __shfl_xor(ti, off, 64);
        if (om > tm || (om == tm && omi < ti)) { tm = om; ti = omi; }
      }
      float ts = 0.0f;
#pragma unroll
      for (int j = 0; j < 5; ++j) ts += expf(t[j] - tm);
#pragma unroll
      for (int off = 32; off > 0; off >>= 1) ts += __shfl_xor(ts, off, 64);
      const float sv = 1.0f / ts;
      const float yv = (1.0f + sv) - sv;  // straight-through value at argmax

      const float4 c4 = ((const float4*)(cb + ((size_t)(g * V_DIM + ti)) * D_DIM))[lane];
      float4 o4;
      o4.x = yv * c4.x; o4.y = yv * c4.y; o4.z = yv * c4.z; o4.w = yv * c4.w;
      ((float4*)q)[(size_t)n * 128 + g * 64 + lane] = o4;
    }
#pragma unroll
    for (int j = 0; j < 5; ++j)
      atomicAdd(&accL[g * V_DIM + lane + 64 * j], pacc5[j]);
  }

  __syncthreads();
  const size_t pb = (size_t)(blockIdx.x & (NBUCKET - 1)) * GV;
  for (int e = tid; e < GV; e += 512) {
    atomicAdd(&mf[pb + e], accL[e]);
    atomicAdd(&mi[pb + e], cntL[e]);
  }
}

// ---------------- Finalize: sum 64 buckets, entropies, outputs ----------------
__global__ __launch_bounds__(256) void finalize_kernel(
    const float* __restrict__ mf, const int* __restrict__ mi,
    float* __restrict__ out3) {
  __shared__ float sA[G_DIM];
  __shared__ float sC[G_DIM];
  if (threadIdx.x < G_DIM) { sA[threadIdx.x] = 0.0f; sC[threadIdx.x] = 0.0f; }
  __syncthreads();

  for (int e = threadIdx.x; e < GV; e += 256) {
    float f = 0.0f; int c = 0;
#pragma unroll
    for (int b = 0; b < NBUCKET; ++b) {
      f += mf[(size_t)b * GV + e];
      c += mi[(size_t)b * GV + e];
    }
    const int g = e / V_DIM;
    const float pa = f * (1.0f / 16384.0f);
    const float ph = (float)c * (1.0f / 16384.0f);
    atomicAdd(&sA[g], pa * logf(pa + 1e-7f));
    atomicAdd(&sC[g], ph * logf(ph + 1e-7f));
  }
  __syncthreads();
  if (threadIdx.x == 0) {
    const float code_p = expf(-sC[0]) + expf(-sC[1]);
    const float prob_p = expf(-sA[0]) + expf(-sA[1]);
    out3[0] = code_p;
    out3[1] = prob_p;
    out3[2] = ((float)GV - prob_p) / (float)GV;
  }
}

extern "C" void kernel_launch(void* const* d_in, const int* in_sizes, int n_in,
                              void* d_out, int out_size, void* d_ws, size_t ws_size,
                              hipStream_t stream) {
  const float* x  = (const float*)d_in[0];  // [8,2048,1024]
  const float* W  = (const float*)d_in[1];  // [640,1024]
  const float* b  = (const float*)d_in[2];  // [640]
  const float* cb = (const float*)d_in[3];  // [1,640,256]
  const float* gn = (const float*)d_in[4];  // [32768,320]
  float* out = (float*)d_out;               // q [16384*512] + 3 scalars

  char* ws = (char*)d_ws;
  _Float16* whT = (_Float16*)ws;             // 1,310,720 B
  float* mf = (float*)(ws + 1310720);        // 64*640*4 = 163,840 B
  int*   mi = (int*)  (ws + 1474560);        // 163,840 B

  hipMemsetAsync(mf, 0, 2 * 163840, stream);

  wsplit_kernel<<<(GV * C_DIM / 8) / 256, 256, 0, stream>>>(W, whT);

  fused_kernel<<<FBLKS, 512, 0, stream>>>(x, whT, b, gn, cb, out, mf, mi);

  finalize_kernel<<<1, 256, 0, stream>>>(mf, mi, out + (size_t)N_ROWS * 512);
}

// Round 2
// 210.702 us; speedup vs baseline: 1.3102x; 1.3102x over previous
//
#include <hip/hip_runtime.h>

// Problem constants
#define N_ROWS 16384   // B*T
#define C_DIM  1024
#define GV     640     // G*V
#define V_DIM  320
#define G_DIM  2
#define D_DIM  256
#define MROWS  64      // rows per fused block
#define FBLKS  (N_ROWS / MROWS)  // 256 = exactly 1 block/CU
#define NBUCKET 64

typedef __attribute__((ext_vector_type(8))) _Float16 half8;
typedef __attribute__((ext_vector_type(4))) _Float16 half4v;
typedef __attribute__((ext_vector_type(4))) float float4v;

#define LDS_AS(p) ((__attribute__((address_space(3))) unsigned int*)(p))
#define GLB_AS(p) ((const __attribute__((address_space(1))) unsigned int*)(p))

// ---------------- W -> fp16 hi, pre-swizzled into 16B-chunk-transposed layout ----
// whT[((kb*4 + c)*640 + n)*8 + h] = (half)W[n][kb*32 + c*8 + h]
// Also zeroes the mf/mi atomic-partial region (81,920 threads x 4 B = 327,680 B),
// replacing the hipMemsetAsync graph node.
__global__ __launch_bounds__(256) void wsplit_kernel(const float* __restrict__ src,
                                                     _Float16* __restrict__ dst,
                                                     int* __restrict__ zr) {
  const int t = blockIdx.x * 256 + threadIdx.x;  // 0..81919
  zr[t] = 0;
  const int n = t % GV;
  const int cc = t / GV;       // 0..127 ; k = cc*8
  const int k = cc * 8;
  const float4 v0 = *(const float4*)(src + (size_t)n * C_DIM + k);
  const float4 v1 = *(const float4*)(src + (size_t)n * C_DIM + k + 4);
  half8 h;
  h[0] = (_Float16)v0.x; h[1] = (_Float16)v0.y; h[2] = (_Float16)v0.z; h[3] = (_Float16)v0.w;
  h[4] = (_Float16)v1.x; h[5] = (_Float16)v1.y; h[6] = (_Float16)v1.z; h[7] = (_Float16)v1.w;
  *(half8*)(dst + (size_t)t * 8) = h;
}

// ---------------- Fused: GEMM (M=64 x N=640 per block) + row ops ----------------
// (unchanged from previous round — isolating the finalize/memset fix)
__global__ __launch_bounds__(512, 2) void fused_kernel(
    const float* __restrict__ x,       // [N_ROWS, C_DIM] fp32
    const _Float16* __restrict__ whT,  // swizzled fp16 hi of W
    const float* __restrict__ bias,    // [GV]
    const float* __restrict__ gn,      // [2*N_ROWS, V_DIM]
    const float* __restrict__ cb,      // [GV, D_DIM]
    float* __restrict__ q,             // [N_ROWS, 512]
    float* __restrict__ mf,            // [NBUCKET, GV] atomic softmax partials (pre-zeroed)
    int* __restrict__ mi) {            // [NBUCKET, GV] atomic argmax counts (pre-zeroed)
  // LDS map (bytes):
  //  [0      , 81920): B hi, 2 buffers x 40960  ([c][n] 16B chunks)
  //  [81920  , 90112): A hi, 2 buffers x 4096   ([c][row] 8B half-chunks)
  //  [90112  , 98304): A lo, 2 buffers x 4096
  //  epilogue: Ldump = 64 x 321 fp32 (82176 B) reuses [0, 82176)
  __shared__ __align__(16) char smemU[98304];
  _Float16* BhL = (_Float16*)smemU;
  _Float16* AhL = (_Float16*)(smemU + 81920);
  _Float16* AlL = (_Float16*)(smemU + 90112);
  float* Ldump  = (float*)smemU;
  __shared__ float accL[GV];
  __shared__ int   cntL[GV];

  const int tid = threadIdx.x;
  const int lane = tid & 63;
  const int w = tid >> 6;          // wave 0..7
  const int m0 = blockIdx.x * MROWS;
  const int frow = lane & 15;
  const int quad = lane >> 4;

  for (int e = tid; e < GV; e += 512) { accL[e] = 0.0f; cntL[e] = 0; }

  // A staging map: thread -> (row ar, 4-float k-chunk ak) of 64x32 fp32 tile
  const int ar = tid >> 3;           // 0..63
  const int ak = (tid & 7) * 4;      // 0,4,...,28
  const int ac = ak >> 3;            // chunk 0..3
  const int ah_off = ak & 7;         // 0 or 4 within 8-half chunk
  const float* xp = x + (size_t)(m0 + ar) * C_DIM + ak;

  float4v acc[4][5];
#pragma unroll
  for (int i = 0; i < 4; ++i)
#pragma unroll
    for (int j = 0; j < 5; ++j) acc[i][j] = (float4v)0.0f;

  // ---- staging helpers ----
  auto stageB = [&](int kb, _Float16* Bh) {
    const _Float16* bsrc = whT + (size_t)kb * 2560 * 8;
#pragma unroll
    for (int s = 0; s < 5; ++s) {
      const int c = s * 512 + tid;   // 2560 16B chunks, lane-linear both sides
      __builtin_amdgcn_global_load_lds(GLB_AS(bsrc + (size_t)c * 8),
                                       LDS_AS(Bh + c * 8), 16, 0, 0);
    }
  };
  auto splitA = [&](const float4& a4, _Float16* Ah, _Float16* Al) {
    const _Float16 h0 = (_Float16)a4.x, h1 = (_Float16)a4.y;
    const _Float16 h2 = (_Float16)a4.z, h3 = (_Float16)a4.w;
    half4v hv, lv;
    hv[0] = h0; hv[1] = h1; hv[2] = h2; hv[3] = h3;
    lv[0] = (_Float16)(a4.x - (float)h0);
    lv[1] = (_Float16)(a4.y - (float)h1);
    lv[2] = (_Float16)(a4.z - (float)h2);
    lv[3] = (_Float16)(a4.w - (float)h3);
    *(half4v*)&Ah[(ac * 64 + ar) * 8 + ah_off] = hv;
    *(half4v*)&Al[(ac * 64 + ar) * 8 + ah_off] = lv;
  };

  // ---- prologue: fill buffer 0, prefetch A regs for kb=1 ----
  float4 a4 = *(const float4*)xp;
  stageB(0, BhL);
  splitA(a4, AhL, AlL);
  a4 = *(const float4*)(xp + 32);
  __syncthreads();

  // ---- main loop: 32 K-iters, single barrier each ----
  for (int kb = 0; kb < 32; ++kb) {
    const int cur = kb & 1;
    _Float16* BhC = BhL + cur * 20480;
    _Float16* AhC = AhL + cur * 2048;
    _Float16* AlC = AlL + cur * 2048;

    // issue next-iter staging into the other buffer BEFORE compute
    if (kb < 31) {
      const int nxt = cur ^ 1;
      stageB(kb + 1, BhL + nxt * 20480);
      splitA(a4, AhL + nxt * 2048, AlL + nxt * 2048);
      if (kb < 30) a4 = *(const float4*)(xp + (kb + 2) * 32);
    }

    half8 ah[4], al[4];
#pragma unroll
    for (int i = 0; i < 4; ++i) {
      ah[i] = *(const half8*)&AhC[(quad * 64 + 16 * i + frow) * 8];
      al[i] = *(const half8*)&AlC[(quad * 64 + 16 * i + frow) * 8];
    }
#pragma unroll
    for (int j = 0; j < 5; ++j) {
      const half8 bh = *(const half8*)&BhC[(quad * 640 + 80 * w + 16 * j + frow) * 8];
#pragma unroll
      for (int i = 0; i < 4; ++i) {
        acc[i][j] = __builtin_amdgcn_mfma_f32_16x16x32_f16(ah[i], bh, acc[i][j], 0, 0, 0);
        acc[i][j] = __builtin_amdgcn_mfma_f32_16x16x32_f16(al[i], bh, acc[i][j], 0, 0, 0);
      }
    }
    __syncthreads();  // drains the early-issued loads (cheap) + protects buffer swap
  }

  // bias for this wave's cols
  float bw[5];
#pragma unroll
  for (int j = 0; j < 5; ++j) bw[j] = bias[80 * w + 16 * j + frow];

  // -------- epilogue: two group phases --------
#pragma unroll
  for (int g = 0; g < G_DIM; ++g) {
    __syncthreads();  // staging/prev-phase LDS dead
    if ((w >> 2) == g) {
      const int cg0 = 80 * (w & 3) + frow;
#pragma unroll
      for (int i = 0; i < 4; ++i)
#pragma unroll
        for (int j = 0; j < 5; ++j)
#pragma unroll
          for (int r = 0; r < 4; ++r)
            Ldump[(16 * i + 4 * quad + r) * 321 + cg0 + 16 * j] = acc[i][j][r] + bw[j];
    }
    __syncthreads();

    float pacc5[5] = {0.0f, 0.0f, 0.0f, 0.0f, 0.0f};
#pragma unroll
    for (int rr = 0; rr < 8; ++rr) {
      const int row = w * 8 + rr;
      const int n = m0 + row;
      const float* gp = gn + (size_t)(2 * n + g) * V_DIM;

      float l[5], t[5];
#pragma unroll
      for (int j = 0; j < 5; ++j) {
        l[j] = Ldump[row * 321 + lane + 64 * j];
        t[j] = (l[j] + gp[lane + 64 * j]) * 0.5f;
      }

      // argmax of l (first index on ties)
      float m = l[0]; int mi_ = lane;
#pragma unroll
      for (int j = 1; j < 5; ++j) {
        const int v = lane + 64 * j;
        if (l[j] > m) { m = l[j]; mi_ = v; }
      }
#pragma unroll
      for (int off = 32; off > 0; off >>= 1) {
        const float om = __shfl_xor(m, off, 64);
        const int omi = __shfl_xor(mi_, off, 64);
        if (om > m || (om == m && omi < mi_)) { m = om; mi_ = omi; }
      }
      if (lane == 0) atomicAdd(&cntL[g * V_DIM + mi_], 1);

      // softmax of l
      float e[5], s = 0.0f;
#pragma unroll
      for (int j = 0; j < 5; ++j) { e[j] = expf(l[j] - m); s += e[j]; }
#pragma unroll
      for (int off = 32; off > 0; off >>= 1) s += __shfl_xor(s, off, 64);
      const float inv = 1.0f / s;
#pragma unroll
      for (int j = 0; j < 5; ++j) pacc5[j] += e[j] * inv;

      // gumbel path
      float tm = t[0]; int ti = lane;
#pragma unroll
      for (int j = 1; j < 5; ++j) {
        const int v = lane + 64 * j;
        if (t[j] > tm) { tm = t[j]; ti = v; }
      }
#pragma unroll
      for (int off = 32; off > 0; off >>= 1) {
        const float om = __shfl_xor(tm, off, 64);
        const int omi = __shfl_xor(ti, off, 64);
        if (om > tm || (om == tm && omi < ti)) { tm = om; ti = omi; }
      }
      float ts = 0.0f;
#pragma unroll
      for (int j = 0; j < 5; ++j) ts += expf(t[j] - tm);
#pragma unroll
      for (int off = 32; off > 0; off >>= 1) ts += __shfl_xor(ts, off, 64);
      const float sv = 1.0f / ts;
      const float yv = (1.0f + sv) - sv;  // straight-through value at argmax

      const float4 c4 = ((const float4*)(cb + ((size_t)(g * V_DIM + ti)) * D_DIM))[lane];
      float4 o4;
      o4.x = yv * c4.x; o4.y = yv * c4.y; o4.z = yv * c4.z; o4.w = yv * c4.w;
      ((float4*)q)[(size_t)n * 128 + g * 64 + lane] = o4;
    }
#pragma unroll
    for (int j = 0; j < 5; ++j)
      atomicAdd(&accL[g * V_DIM + lane + 64 * j], pacc5[j]);
  }

  __syncthreads();
  const size_t pb = (size_t)(blockIdx.x & (NBUCKET - 1)) * GV;
  for (int e = tid; e < GV; e += 512) {
    atomicAdd(&mf[pb + e], accL[e]);
    atomicAdd(&mi[pb + e], cntL[e]);
  }
}

// ---------------- Finalize: sum 64 buckets, entropies, outputs ----------------
// 640 threads = 10 waves. Waves 0-4 handle group 0 (e in [0,320)), waves 5-9
// group 1 — wave-uniform g. Bucket sum with bounded unroll (no spill), then
// per-wave shuffle reduction; only 10 LDS atomics per array (was 640
// serialized same-address adds). Reads are lane-coalesced (256 B/wave).
__global__ __launch_bounds__(640) void finalize_kernel(
    const float* __restrict__ mf, const int* __restrict__ mi,
    float* __restrict__ out3) {
  __shared__ float sA[G_DIM];
  __shared__ float sC[G_DIM];
  const int t = threadIdx.x;        // 0..639 == e
  if (t < G_DIM) { sA[t] = 0.0f; sC[t] = 0.0f; }
  __syncthreads();

  const int g = t / V_DIM;          // wave-uniform (V_DIM=320 = 5 waves)
  float f = 0.0f;
  int   c = 0;
#pragma unroll 8
  for (int b = 0; b < NBUCKET; ++b) {
    f += mf[(size_t)b * GV + t];
    c += mi[(size_t)b * GV + t];
  }
  const float pa = f * (1.0f / 16384.0f);
  const float ph = (float)c * (1.0f / 16384.0f);
  float a = pa * logf(pa + 1e-7f);
  float h = ph * logf(ph + 1e-7f);
#pragma unroll
  for (int off = 32; off > 0; off >>= 1) {
    a += __shfl_xor(a, off, 64);
    h += __shfl_xor(h, off, 64);
  }
  if ((t & 63) == 0) {
    atomicAdd(&sA[g], a);
    atomicAdd(&sC[g], h);
  }
  __syncthreads();
  if (t == 0) {
    const float code_p = expf(-sC[0]) + expf(-sC[1]);
    const float prob_p = expf(-sA[0]) + expf(-sA[1]);
    out3[0] = code_p;
    out3[1] = prob_p;
    out3[2] = ((float)GV - prob_p) / (float)GV;
  }
}

extern "C" void kernel_launch(void* const* d_in, const int* in_sizes, int n_in,
                              void* d_out, int out_size, void* d_ws, size_t ws_size,
                              hipStream_t stream) {
  const float* x  = (const float*)d_in[0];  // [8,2048,1024]
  const float* W  = (const float*)d_in[1];  // [640,1024]
  const float* b  = (const float*)d_in[2];  // [640]
  const float* cb = (const float*)d_in[3];  // [1,640,256]
  const float* gn = (const float*)d_in[4];  // [32768,320]
  float* out = (float*)d_out;               // q [16384*512] + 3 scalars

  char* ws = (char*)d_ws;
  _Float16* whT = (_Float16*)ws;             // 1,310,720 B
  float* mf = (float*)(ws + 1310720);        // 64*640*4 = 163,840 B
  int*   mi = (int*)  (ws + 1474560);        // 163,840 B

  // wsplit also zeroes mf+mi (327,680 B = 81,920 threads x 4 B)
  wsplit_kernel<<<(GV * C_DIM / 8) / 256, 256, 0, stream>>>(W, whT, (int*)mf);

  fused_kernel<<<FBLKS, 512, 0, stream>>>(x, whT, b, gn, cb, out, mf, mi);

  finalize_kernel<<<1, 640, 0, stream>>>(mf, mi, out + (size_t)N_ROWS * 512);
}